// Round 7
// baseline (866.807 us; speedup 1.0000x reference)
//
#include <hip/hip_runtime.h>

// Problem constants
#define BN   8
#define CC   256
#define HH   64
#define WW   64
#define GG   8
#define CG   32
#define KKK  9
#define OO   256
#define HW   (HH*WW)
#define NPAD 224
#define NOUT 216

typedef __attribute__((ext_vector_type(8))) _Float16 half8;
typedef __attribute__((ext_vector_type(4))) _Float16 half4;
typedef __attribute__((ext_vector_type(4))) float f32x4;

union U4H8 { uint4 u; half8 h; };

// ---------------------------------------------------------------------------
// K0a: repack w_out [O][C][3][3] -> wt3 f16 [g*9+kk][o 256][cg 32]
// ---------------------------------------------------------------------------
__global__ void repack_w(const float* __restrict__ w_out, _Float16* __restrict__ wt3) {
    int idx = blockIdx.x * 256 + threadIdx.x;
    if (idx >= GG * KKK * CG * OO) return;
    int cg = idx & 31;
    int o  = (idx >> 5) & 255;
    int s  = idx >> 13;
    int kk = s % 9;
    int g  = s / 9;
    wt3[idx] = (_Float16)w_out[o * 2304 + (g * 32 + cg) * 9 + kk];
}

// ---------------------------------------------------------------------------
// K0b: repack conv weights -> wt_conv f16 [tap][oc 224][c 256]; also bias[224]
// ---------------------------------------------------------------------------
__global__ void repack_conv(const float* __restrict__ w_off, const float* __restrict__ b_off,
                            const float* __restrict__ w_attn, const float* __restrict__ b_attn,
                            _Float16* __restrict__ wt_conv, float* __restrict__ bias_c) {
    int idx = blockIdx.x * 256 + threadIdx.x;
    if (idx >= 9 * NPAD * 256) return;
    int c = idx & 255;
    int r = idx >> 8;
    int n = r % NPAD;
    int tap = r / NPAD;
    float v = 0.f;
    if (n < 144)      v = w_off[(n * 256 + c) * 9 + tap];
    else if (n < 216) v = w_attn[((n - 144) * 256 + c) * 9 + tap];
    wt_conv[(tap * NPAD + n) * 256 + c] = (_Float16)v;
    if (idx < NPAD) {
        float bv = 0.f;
        if (idx < 144)      bv = b_off[idx];
        else if (idx < 216) bv = b_attn[idx - 144];
        bias_c[idx] = bv;
    }
}

// ---------------------------------------------------------------------------
// K0c: repack x f32 NCHW -> x_h f16 NHWC [b][y][x][c]
// ---------------------------------------------------------------------------
__global__ __launch_bounds__(256) void repack_x(const float* __restrict__ x,
                                                _Float16* __restrict__ x_h) {
    __shared__ _Float16 T[64][264];
    const int bid = blockIdx.x;
    const int b = bid & 7, h = bid >> 3;
    const int t = threadIdx.x;   // = channel
    const float* src = x + (((long)(b * 256 + t)) << 12) + h * 64;
    #pragma unroll
    for (int i = 0; i < 16; ++i) {
        float4 f = ((const float4*)src)[i];
        T[i * 4 + 0][t] = (_Float16)f.x;
        T[i * 4 + 1][t] = (_Float16)f.y;
        T[i * 4 + 2][t] = (_Float16)f.z;
        T[i * 4 + 3][t] = (_Float16)f.w;
    }
    __syncthreads();
    _Float16* dst = x_h + (((long)(b * 4096 + h * 64)) << 8);
    #pragma unroll
    for (int it = 0; it < 8; ++it) {
        int idx = it * 256 + t;
        int px = idx >> 5, ch = idx & 31;
        uint4 v = *(const uint4*)&T[px][ch * 8];
        *(uint4*)(dst + px * 256 + ch * 8) = v;
    }
}

// ---------------------------------------------------------------------------
// K1: implicit-GEMM conv via f16 MFMA, 2-deep register pipeline.
// Block = 256 thr (4 waves), M=64 px x N=112 oc (half); grid 1024 = (b,h,half).
// 72 stages (tap x 32-ch chunk); loads for stage s issued at s-2.
// ---------------------------------------------------------------------------
__global__ __launch_bounds__(256, 4) void conv_mfma(
    const _Float16* __restrict__ x_h, const _Float16* __restrict__ wt_conv,
    const float* __restrict__ bias_c, float* __restrict__ conv_buf) {
    __shared__ _Float16 Ald[64][40];    // 5 KB
    __shared__ _Float16 Bld[112][40];   // 8.75 KB

    const int bid = blockIdx.x;
    const int b = bid & 7, h = (bid >> 3) & 63, half = bid >> 9;
    const int t = threadIdx.x;
    const int lane = t & 63;
    const int mt = t >> 6;          // wave = M-tile
    const int px = t >> 2, cq = t & 3;
    const int bn = t >> 2, bp = t & 3;
    const bool hasB2 = (t < 192);   // rows 64..111

    f32x4 acc[7];
    #pragma unroll
    for (int i = 0; i < 7; ++i) acc[i] = (f32x4){0.f, 0.f, 0.f, 0.f};

    const _Float16* xb = x_h + ((long)b << 20) + cq * 8;
    const _Float16* wb = wt_conv + (long)(half * 112) * 256;

    // 2-deep pipeline state
    uint4 aR[2]; bool vA[2];
    uint4 P0[2], P1[2];

    // ---- preamble: issue stages 0 and 1 ----
    #pragma unroll
    for (int s = 0; s < 2; ++s) {
        int tap = s >> 3, cc = s & 7;           // tap 0, cc = s
        int ti = tap / 3, tj = tap % 3;
        int y = h + ti - 1, xc = px + tj - 1;
        vA[s] = ((unsigned)y < 64u) && ((unsigned)xc < 64u);
        int yc = min(max(y, 0), 63), xcc = min(max(xc, 0), 63);
        aR[s] = *(const uint4*)(xb + ((long)(yc * 64 + xcc)) * 256 + cc * 32);
        const _Float16* ws = wb + (long)tap * NPAD * 256 + cc * 32;
        P0[s] = *(const uint4*)(ws + bn * 256 + bp * 8);
        if (hasB2) P1[s] = *(const uint4*)(ws + (bn + 64) * 256 + bp * 8);
    }

    for (int ss = 0; ss < 72; ++ss) {
        const int p = ss & 1;
        // ---- LDS write from set p (loads issued 2 stages ago) ----
        {
            uint4 az = vA[p] ? aR[p] : make_uint4(0u, 0u, 0u, 0u);
            *(uint4*)&Ald[px][cq * 8] = az;
            *(uint4*)&Bld[bn][bp * 8] = P0[p];
            if (hasB2) *(uint4*)&Bld[bn + 64][bp * 8] = P1[p];
        }
        // ---- issue loads for stage ss+2 into set p ----
        if (ss + 2 < 72) {
            int sn = ss + 2;
            int tap = sn >> 3, cc = sn & 7;
            int ti = tap / 3, tj = tap % 3;
            int y = h + ti - 1, xc = px + tj - 1;
            vA[p] = ((unsigned)y < 64u) && ((unsigned)xc < 64u);
            int yc = min(max(y, 0), 63), xcc = min(max(xc, 0), 63);
            aR[p] = *(const uint4*)(xb + ((long)(yc * 64 + xcc)) * 256 + cc * 32);
            const _Float16* ws = wb + (long)tap * NPAD * 256 + cc * 32;
            P0[p] = *(const uint4*)(ws + bn * 256 + bp * 8);
            if (hasB2) P1[p] = *(const uint4*)(ws + (bn + 64) * 256 + bp * 8);
        }
        __syncthreads();

        // ---- MFMA: 1 M-tile x 7 N-tiles per wave ----
        const int k0 = (lane >> 4) * 8;
        half8 a = *(const half8*)&Ald[mt * 16 + (lane & 15)][k0];
        #pragma unroll
        for (int j = 0; j < 7; ++j) {
            half8 bf = *(const half8*)&Bld[j * 16 + (lane & 15)][k0];
            acc[j] = __builtin_amdgcn_mfma_f32_16x16x32_f16(a, bf, acc[j], 0, 0, 0);
        }
        __syncthreads();
    }

    // ---- epilogue ----
    #pragma unroll
    for (int i = 0; i < 7; ++i) {
        int oc = half * 112 + i * 16 + (lane & 15);
        if (oc < NOUT) {
            int colb = mt * 16 + ((lane >> 4) * 4);
            float bb = bias_c[oc];
            float4 v = make_float4(acc[i][0] + bb, acc[i][1] + bb,
                                   acc[i][2] + bb, acc[i][3] + bb);
            *(float4*)&conv_buf[((long)b * NOUT + oc) * HW + h * WW + colb] = v;
        }
    }
}

// ---------------------------------------------------------------------------
// masked bilinear weights + clamped corner indices
// ---------------------------------------------------------------------------
__device__ __forceinline__ void calc_coords(int h, int px, int ki, int kj,
    float dy, float dx,
    int& i00, int& i01, int& i10, int& i11,
    float& u00, float& u01, float& u10, float& u11) {
    float py  = (float)(h - 1 + ki) + dy;
    float pxf = (float)(px - 1 + kj) + dx;
    float y0f = floorf(py), x0f = floorf(pxf);
    int y0 = (int)y0f, x0 = (int)x0f;
    float wy1 = py - y0f, wx1 = pxf - x0f;
    float wy0 = 1.f - wy1, wx0 = 1.f - wx1;
    int y1 = y0 + 1, x1 = x0 + 1;
    float m00 = (((unsigned)y0 < 64u) && ((unsigned)x0 < 64u)) ? 1.f : 0.f;
    float m01 = (((unsigned)y0 < 64u) && ((unsigned)x1 < 64u)) ? 1.f : 0.f;
    float m10 = (((unsigned)y1 < 64u) && ((unsigned)x0 < 64u)) ? 1.f : 0.f;
    float m11 = (((unsigned)y1 < 64u) && ((unsigned)x1 < 64u)) ? 1.f : 0.f;
    int cy0 = min(max(y0, 0), 63), cy1 = min(max(y1, 0), 63);
    int cx0 = min(max(x0, 0), 63), cx1 = min(max(x1, 0), 63);
    u00 = wy0 * wx0 * m00; u01 = wy0 * wx1 * m01;
    u10 = wy1 * wx0 * m10; u11 = wy1 * wx1 * m11;
    i00 = cy0 * 64 + cx0; i01 = cy0 * 64 + cx1;
    i10 = cy1 * 64 + cx0; i11 = cy1 * 64 + cx1;
}

// ---------------------------------------------------------------------------
// K3: fused softmax + sampling + modulation + MFMA, 2-deep register pipeline.
// Block = 256 thr (4 waves), M=64 px x N=128 oc (half); grid 1024 = (b,h,half).
// Gathers/B for stage s issued at s-2; dy/dx rotated 1 stage ahead of coords.
// ---------------------------------------------------------------------------
__global__ __launch_bounds__(256, 4) void sample_gemm_mfma(
    const _Float16* __restrict__ x_h, const float* __restrict__ conv_buf,
    const _Float16* __restrict__ wt3,
    const float* __restrict__ b_out, float* __restrict__ out) {
    __shared__ _Float16 Ald[64][40];    // 5 KB
    __shared__ _Float16 Bld[128][40];   // 10 KB
    __shared__ float attnL[72 * 64];    // 18 KB

    const int bid = blockIdx.x;
    const int b = bid & 7, h = (bid >> 3) & 63, half = bid >> 9;
    const int t = threadIdx.x;
    const int lane = t & 63;
    const int wv = t >> 6;
    const int mh = wv & 1;
    const int nh = wv >> 1;
    const int px = t >> 2, cq = t & 3;
    const int bn = t >> 2, bp = t & 3;

    f32x4 acc[2][4];
    #pragma unroll
    for (int i = 0; i < 2; ++i)
        #pragma unroll
        for (int j = 0; j < 4; ++j) acc[i][j] = (f32x4){0.f, 0.f, 0.f, 0.f};

    const float* cbase = conv_buf + (long)b * NOUT * HW + h * WW;
    const _Float16* xbase = x_h + ((long)b << 20) + cq * 8;

    // ---- preamble 1: softmax over 9 taps -> attnL[s][px] ----
    #pragma unroll
    for (int i = 0; i < 2; ++i) {
        int pi = t + i * 256;            // (g 0..7, px 0..63)
        int ppx = pi & 63, g = pi >> 6;
        const float* ap = cbase + (long)(144 + g * 9) * HW + ppx;
        float v[9];
        float m = -1e30f;
        #pragma unroll
        for (int k = 0; k < 9; ++k) { v[k] = ap[k * HW]; m = fmaxf(m, v[k]); }
        float ssum = 0.f;
        #pragma unroll
        for (int k = 0; k < 9; ++k) { v[k] = __expf(v[k] - m); ssum += v[k]; }
        float inv = 1.f / ssum;
        #pragma unroll
        for (int k = 0; k < 9; ++k) attnL[(g * 9 + k) * 64 + ppx] = v[k] * inv;
    }

    // ---- preamble 2: 2-deep prefetch (stages 0 and 1) + dy/dx for stage 2 ----
    uint4 q[2][4];
    float u[2][4];
    uint4 pb[2][2];
    float dyR, dxR;
    #pragma unroll
    for (int s = 0; s < 2; ++s) {
        float dy = cbase[(s * 2) * HW + px], dx = cbase[(s * 2 + 1) * HW + px];
        int i00, i01, i10, i11;
        calc_coords(h, px, s / 3, s % 3, dy, dx, i00, i01, i10, i11,
                    u[s][0], u[s][1], u[s][2], u[s][3]);
        q[s][0] = *(const uint4*)(xbase + (long)i00 * 256);
        q[s][1] = *(const uint4*)(xbase + (long)i01 * 256);
        q[s][2] = *(const uint4*)(xbase + (long)i10 * 256);
        q[s][3] = *(const uint4*)(xbase + (long)i11 * 256);
        const _Float16* ws = wt3 + (long)s * 8192 + (long)half * 4096;
        pb[s][0] = *(const uint4*)(ws + bn * 32 + bp * 8);
        pb[s][1] = *(const uint4*)(ws + (bn + 64) * 32 + bp * 8);
    }
    dyR = cbase[4 * HW + px]; dxR = cbase[5 * HW + px];
    __syncthreads();   // attnL ready

    for (int ss = 0; ss < 72; ++ss) {
        const int p = ss & 1;
        // ---- LDS write from set p (loads issued 2 stages ago) ----
        {
            *(uint4*)&Bld[bn][bp * 8] = pb[p][0];
            *(uint4*)&Bld[bn + 64][bp * 8] = pb[p][1];
            float av = attnL[ss * 64 + px];
            U4H8 a00, a01, a10, a11;
            a00.u = q[p][0]; a01.u = q[p][1]; a10.u = q[p][2]; a11.u = q[p][3];
            half8 rr = a00.h * (_Float16)u[p][0] + a01.h * (_Float16)u[p][1]
                     + a10.h * (_Float16)u[p][2] + a11.h * (_Float16)u[p][3];
            rr = rr * (_Float16)av;
            *(half8*)&Ald[px][cq * 8] = rr;
        }
        // ---- issue loads for stage ss+2 into set p ----
        if (ss + 2 < 72) {
            int sn = ss + 2;
            int g = sn / 9, kk = sn % 9;
            int i00, i01, i10, i11;
            calc_coords(h, px, kk / 3, kk % 3, dyR, dxR, i00, i01, i10, i11,
                        u[p][0], u[p][1], u[p][2], u[p][3]);
            const _Float16* xg = xbase + g * 32;
            q[p][0] = *(const uint4*)(xg + (long)i00 * 256);
            q[p][1] = *(const uint4*)(xg + (long)i01 * 256);
            q[p][2] = *(const uint4*)(xg + (long)i10 * 256);
            q[p][3] = *(const uint4*)(xg + (long)i11 * 256);
            const _Float16* ws = wt3 + (long)sn * 8192 + (long)half * 4096;
            pb[p][0] = *(const uint4*)(ws + bn * 32 + bp * 8);
            pb[p][1] = *(const uint4*)(ws + (bn + 64) * 32 + bp * 8);
        }
        // ---- rotate dy/dx one stage ahead of coord calc ----
        if (ss + 3 < 72) {
            int sf = ss + 3;
            dyR = cbase[(sf * 2) * HW + px];
            dxR = cbase[(sf * 2 + 1) * HW + px];
        }
        __syncthreads();

        // ---- MFMA: 2 M-tiles x 4 N-tiles per wave ----
        const int k0 = (lane >> 4) * 8;
        half8 a0 = *(const half8*)&Ald[mh * 32 + (lane & 15)][k0];
        half8 a1 = *(const half8*)&Ald[mh * 32 + 16 + (lane & 15)][k0];
        #pragma unroll
        for (int j = 0; j < 4; ++j) {
            half8 bf = *(const half8*)&Bld[(nh * 4 + j) * 16 + (lane & 15)][k0];
            acc[0][j] = __builtin_amdgcn_mfma_f32_16x16x32_f16(a0, bf, acc[0][j], 0, 0, 0);
            acc[1][j] = __builtin_amdgcn_mfma_f32_16x16x32_f16(a1, bf, acc[1][j], 0, 0, 0);
        }
        __syncthreads();
    }

    // ---- epilogue ----
    #pragma unroll
    for (int mi = 0; mi < 2; ++mi) {
        int px0 = mh * 32 + mi * 16 + (lane >> 4) * 4;
        #pragma unroll
        for (int j = 0; j < 4; ++j) {
            int oc = half * 128 + (nh * 4 + j) * 16 + (lane & 15);
            float bb = b_out[oc];
            float4 v = make_float4(acc[mi][j][0] + bb, acc[mi][j][1] + bb,
                                   acc[mi][j][2] + bb, acc[mi][j][3] + bb);
            *(float4*)&out[((long)b * OO + oc) * HW + h * WW + px0] = v;
        }
    }
}

// ---------------------------------------------------------------------------
extern "C" void kernel_launch(void* const* d_in, const int* in_sizes, int n_in,
                              void* d_out, int out_size, void* d_ws, size_t ws_size,
                              hipStream_t stream) {
    const float* x      = (const float*)d_in[0];
    const float* w_off  = (const float*)d_in[1];
    const float* b_off  = (const float*)d_in[2];
    const float* w_attn = (const float*)d_in[3];
    const float* b_attn = (const float*)d_in[4];
    const float* w_out  = (const float*)d_in[5];
    const float* b_out  = (const float*)d_in[6];
    float* out = (float*)d_out;

    _Float16* x_h     = (_Float16*)d_ws;                    // 8,388,608 halves
    float* conv_buf   = (float*)(x_h + 8388608);            // 7,077,888 floats
    _Float16* wt3     = (_Float16*)(conv_buf + 7077888);    // 589,824 halves
    _Float16* wt_conv = wt3 + 589824;                       // 516,096 halves
    float* bias_c     = (float*)(wt_conv + 516096);         // 224 floats

    repack_w<<<dim3((589824 + 255) / 256), dim3(256), 0, stream>>>(w_out, wt3);
    repack_conv<<<dim3((9 * NPAD * 256 + 255) / 256), dim3(256), 0, stream>>>(
        w_off, b_off, w_attn, b_attn, wt_conv, bias_c);
    repack_x<<<dim3(512), dim3(256), 0, stream>>>(x, x_h);

    conv_mfma<<<dim3(1024), dim3(256), 0, stream>>>(x_h, wt_conv, bias_c, conv_buf);

    sample_gemm_mfma<<<dim3(1024), dim3(256), 0, stream>>>(
        x_h, conv_buf, wt3, b_out, out);
}

// Round 8
// 271.642 us; speedup vs baseline: 3.1910x; 3.1910x over previous
//
#include <hip/hip_runtime.h>

// Problem constants
#define BN   8
#define CC   256
#define HH   64
#define WW   64
#define GG   8
#define CG   32
#define KKK  9
#define OO   256
#define HW   (HH*WW)
#define NPAD 224
#define NOUT 216

typedef __attribute__((ext_vector_type(8))) _Float16 half8;
typedef __attribute__((ext_vector_type(4))) _Float16 half4;
typedef __attribute__((ext_vector_type(4))) float f32x4;

union U4H8 { uint4 u; half8 h; };

// ---------------------------------------------------------------------------
// K0a: repack w_out [O][C][3][3] -> wt3 f16 [g*9+kk][o 256][cg 32]
// ---------------------------------------------------------------------------
__global__ void repack_w(const float* __restrict__ w_out, _Float16* __restrict__ wt3) {
    int idx = blockIdx.x * 256 + threadIdx.x;
    if (idx >= GG * KKK * CG * OO) return;
    int cg = idx & 31;
    int o  = (idx >> 5) & 255;
    int s  = idx >> 13;
    int kk = s % 9;
    int g  = s / 9;
    wt3[idx] = (_Float16)w_out[o * 2304 + (g * 32 + cg) * 9 + kk];
}

// ---------------------------------------------------------------------------
// K0b: repack conv weights -> wt_conv f16 [tap][oc 224][c 256]; also bias[224]
// ---------------------------------------------------------------------------
__global__ void repack_conv(const float* __restrict__ w_off, const float* __restrict__ b_off,
                            const float* __restrict__ w_attn, const float* __restrict__ b_attn,
                            _Float16* __restrict__ wt_conv, float* __restrict__ bias_c) {
    int idx = blockIdx.x * 256 + threadIdx.x;
    if (idx >= 9 * NPAD * 256) return;
    int c = idx & 255;
    int r = idx >> 8;
    int n = r % NPAD;
    int tap = r / NPAD;
    float v = 0.f;
    if (n < 144)      v = w_off[(n * 256 + c) * 9 + tap];
    else if (n < 216) v = w_attn[((n - 144) * 256 + c) * 9 + tap];
    wt_conv[(tap * NPAD + n) * 256 + c] = (_Float16)v;
    if (idx < NPAD) {
        float bv = 0.f;
        if (idx < 144)      bv = b_off[idx];
        else if (idx < 216) bv = b_attn[idx - 144];
        bias_c[idx] = bv;
    }
}

// ---------------------------------------------------------------------------
// K0c: repack x f32 NCHW -> x_h f16 NHWC [b][y][x][c]
// ---------------------------------------------------------------------------
__global__ __launch_bounds__(256) void repack_x(const float* __restrict__ x,
                                                _Float16* __restrict__ x_h) {
    __shared__ _Float16 T[64][264];
    const int bid = blockIdx.x;
    const int b = bid & 7, h = bid >> 3;
    const int t = threadIdx.x;   // = channel
    const float* src = x + (((long)(b * 256 + t)) << 12) + h * 64;
    #pragma unroll
    for (int i = 0; i < 16; ++i) {
        float4 f = ((const float4*)src)[i];
        T[i * 4 + 0][t] = (_Float16)f.x;
        T[i * 4 + 1][t] = (_Float16)f.y;
        T[i * 4 + 2][t] = (_Float16)f.z;
        T[i * 4 + 3][t] = (_Float16)f.w;
    }
    __syncthreads();
    _Float16* dst = x_h + (((long)(b * 4096 + h * 64)) << 8);
    #pragma unroll
    for (int it = 0; it < 8; ++it) {
        int idx = it * 256 + t;
        int px = idx >> 5, ch = idx & 31;
        uint4 v = *(const uint4*)&T[px][ch * 8];
        *(uint4*)(dst + px * 256 + ch * 8) = v;
    }
}

// ---------------------------------------------------------------------------
// K1: implicit-GEMM conv via f16 MFMA, 2-deep STATIC register pipeline.
// Block = 256 thr (4 waves), M=64 px x N=112 oc (half); grid 1024 = (b,h,half).
// 72 stages (tap x 32-ch chunk); stage loop unrolled x2 so the two pipeline
// register sets are statically named (NO dynamic indexing -> no scratch).
// ---------------------------------------------------------------------------
__global__ __launch_bounds__(256, 4) void conv_mfma(
    const _Float16* __restrict__ x_h, const _Float16* __restrict__ wt_conv,
    const float* __restrict__ bias_c, float* __restrict__ conv_buf) {
    __shared__ _Float16 Ald[64][40];    // 5 KB
    __shared__ _Float16 Bld[112][40];   // 8.75 KB

    const int bid = blockIdx.x;
    const int b = bid & 7, h = (bid >> 3) & 63, half = bid >> 9;
    const int t = threadIdx.x;
    const int lane = t & 63;
    const int mt = t >> 6;          // wave = M-tile
    const int px = t >> 2, cq = t & 3;
    const int bn = t >> 2, bp = t & 3;
    const bool hasB2 = (t < 192);   // rows 64..111

    f32x4 acc[7];
    #pragma unroll
    for (int i = 0; i < 7; ++i) acc[i] = (f32x4){0.f, 0.f, 0.f, 0.f};

    const _Float16* xb = x_h + ((long)b << 20) + cq * 8;
    const _Float16* wb = wt_conv + (long)(half * 112) * 256;

    // static 2-deep pipeline state
    uint4 aR0, aR1; bool vA0, vA1;
    uint4 P00, P10, P01, P11;

#define CONV_ISSUE(AR, VA, Q0, Q1, S) {                                     \
        int tap_ = (S) >> 3, cc_ = (S) & 7;                                 \
        int ti_ = tap_ / 3, tj_ = tap_ % 3;                                 \
        int y_ = h + ti_ - 1, xc_ = px + tj_ - 1;                           \
        VA = ((unsigned)y_ < 64u) && ((unsigned)xc_ < 64u);                 \
        int yc_ = min(max(y_, 0), 63), xcc_ = min(max(xc_, 0), 63);         \
        AR = *(const uint4*)(xb + ((long)(yc_ * 64 + xcc_)) * 256 + cc_ * 32); \
        const _Float16* ws_ = wb + (long)tap_ * NPAD * 256 + cc_ * 32;      \
        Q0 = *(const uint4*)(ws_ + bn * 256 + bp * 8);                      \
        if (hasB2) Q1 = *(const uint4*)(ws_ + (bn + 64) * 256 + bp * 8);    \
    }

#define CONV_WRITE(AR, VA, Q0, Q1) {                                        \
        uint4 az_ = VA ? AR : make_uint4(0u, 0u, 0u, 0u);                   \
        *(uint4*)&Ald[px][cq * 8] = az_;                                    \
        *(uint4*)&Bld[bn][bp * 8] = Q0;                                     \
        if (hasB2) *(uint4*)&Bld[bn + 64][bp * 8] = Q1;                     \
    }

#define CONV_MFMA() {                                                       \
        const int k0_ = (lane >> 4) * 8;                                    \
        half8 a_ = *(const half8*)&Ald[mt * 16 + (lane & 15)][k0_];         \
        _Pragma("unroll")                                                   \
        for (int j = 0; j < 7; ++j) {                                       \
            half8 bf_ = *(const half8*)&Bld[j * 16 + (lane & 15)][k0_];     \
            acc[j] = __builtin_amdgcn_mfma_f32_16x16x32_f16(a_, bf_, acc[j], 0, 0, 0); \
        }                                                                   \
    }

    // preamble: stages 0,1
    CONV_ISSUE(aR0, vA0, P00, P10, 0);
    CONV_ISSUE(aR1, vA1, P01, P11, 1);

    for (int ss = 0; ss < 72; ss += 2) {
        // ---- even stage (set 0) ----
        CONV_WRITE(aR0, vA0, P00, P10);
        if (ss + 2 < 72) CONV_ISSUE(aR0, vA0, P00, P10, ss + 2);
        __syncthreads();
        CONV_MFMA();
        __syncthreads();
        // ---- odd stage (set 1) ----
        CONV_WRITE(aR1, vA1, P01, P11);
        if (ss + 3 < 72) CONV_ISSUE(aR1, vA1, P01, P11, ss + 3);
        __syncthreads();
        CONV_MFMA();
        __syncthreads();
    }
#undef CONV_ISSUE
#undef CONV_WRITE
#undef CONV_MFMA

    // ---- epilogue ----
    #pragma unroll
    for (int i = 0; i < 7; ++i) {
        int oc = half * 112 + i * 16 + (lane & 15);
        if (oc < NOUT) {
            int colb = mt * 16 + ((lane >> 4) * 4);
            float bb = bias_c[oc];
            float4 v = make_float4(acc[i][0] + bb, acc[i][1] + bb,
                                   acc[i][2] + bb, acc[i][3] + bb);
            *(float4*)&conv_buf[((long)b * NOUT + oc) * HW + h * WW + colb] = v;
        }
    }
}

// ---------------------------------------------------------------------------
// masked bilinear weights + clamped corner indices
// ---------------------------------------------------------------------------
__device__ __forceinline__ void calc_coords(int h, int px, int ki, int kj,
    float dy, float dx,
    int& i00, int& i01, int& i10, int& i11,
    float& u00, float& u01, float& u10, float& u11) {
    float py  = (float)(h - 1 + ki) + dy;
    float pxf = (float)(px - 1 + kj) + dx;
    float y0f = floorf(py), x0f = floorf(pxf);
    int y0 = (int)y0f, x0 = (int)x0f;
    float wy1 = py - y0f, wx1 = pxf - x0f;
    float wy0 = 1.f - wy1, wx0 = 1.f - wx1;
    int y1 = y0 + 1, x1 = x0 + 1;
    float m00 = (((unsigned)y0 < 64u) && ((unsigned)x0 < 64u)) ? 1.f : 0.f;
    float m01 = (((unsigned)y0 < 64u) && ((unsigned)x1 < 64u)) ? 1.f : 0.f;
    float m10 = (((unsigned)y1 < 64u) && ((unsigned)x0 < 64u)) ? 1.f : 0.f;
    float m11 = (((unsigned)y1 < 64u) && ((unsigned)x1 < 64u)) ? 1.f : 0.f;
    int cy0 = min(max(y0, 0), 63), cy1 = min(max(y1, 0), 63);
    int cx0 = min(max(x0, 0), 63), cx1 = min(max(x1, 0), 63);
    u00 = wy0 * wx0 * m00; u01 = wy0 * wx1 * m01;
    u10 = wy1 * wx0 * m10; u11 = wy1 * wx1 * m11;
    i00 = cy0 * 64 + cx0; i01 = cy0 * 64 + cx1;
    i10 = cy1 * 64 + cx0; i11 = cy1 * 64 + cx1;
}

// ---------------------------------------------------------------------------
// K3: fused softmax + sampling + modulation + MFMA, 2-deep STATIC pipeline.
// Block = 256 thr (4 waves), M=64 px x N=128 oc (half); grid 1024 = (b,h,half).
// Stage loop unrolled x2: even stage -> set0 regs, odd -> set1 (no scratch).
// ---------------------------------------------------------------------------
__global__ __launch_bounds__(256, 4) void sample_gemm_mfma(
    const _Float16* __restrict__ x_h, const float* __restrict__ conv_buf,
    const _Float16* __restrict__ wt3,
    const float* __restrict__ b_out, float* __restrict__ out) {
    __shared__ _Float16 Ald[64][40];    // 5 KB
    __shared__ _Float16 Bld[128][40];   // 10 KB
    __shared__ float attnL[72 * 64];    // 18 KB

    const int bid = blockIdx.x;
    const int b = bid & 7, h = (bid >> 3) & 63, half = bid >> 9;
    const int t = threadIdx.x;
    const int lane = t & 63;
    const int wv = t >> 6;
    const int mh = wv & 1;
    const int nh = wv >> 1;
    const int px = t >> 2, cq = t & 3;
    const int bn = t >> 2, bp = t & 3;

    f32x4 acc[2][4];
    #pragma unroll
    for (int i = 0; i < 2; ++i)
        #pragma unroll
        for (int j = 0; j < 4; ++j) acc[i][j] = (f32x4){0.f, 0.f, 0.f, 0.f};

    const float* cbase = conv_buf + (long)b * NOUT * HW + h * WW;
    const _Float16* xbase = x_h + ((long)b << 20) + cq * 8;

    // ---- preamble 1: softmax over 9 taps -> attnL[s][px] ----
    #pragma unroll
    for (int i = 0; i < 2; ++i) {
        int pi = t + i * 256;            // (g 0..7, px 0..63)
        int ppx = pi & 63, g = pi >> 6;
        const float* ap = cbase + (long)(144 + g * 9) * HW + ppx;
        float v[9];
        float m = -1e30f;
        #pragma unroll
        for (int k = 0; k < 9; ++k) { v[k] = ap[k * HW]; m = fmaxf(m, v[k]); }
        float ssum = 0.f;
        #pragma unroll
        for (int k = 0; k < 9; ++k) { v[k] = __expf(v[k] - m); ssum += v[k]; }
        float inv = 1.f / ssum;
        #pragma unroll
        for (int k = 0; k < 9; ++k) attnL[(g * 9 + k) * 64 + ppx] = v[k] * inv;
    }

    // static 2-deep pipeline state
    uint4 qa0, qb0, qc0, qd0, qa1, qb1, qc1, qd1;
    float ua0, ub0, uc0, ud0, ua1, ub1, uc1, ud1;
    uint4 pA0, pB0, pA1, pB1;
    float dyR, dxR;

#define SAMP_ISSUE(QA, QB, QC, QD, UA, UB, UC, UD, PA, PB, S, DY, DX) {     \
        int g_ = (S) / 9, kk_ = (S) % 9;                                    \
        int i00_, i01_, i10_, i11_;                                         \
        calc_coords(h, px, kk_ / 3, kk_ % 3, DY, DX,                        \
                    i00_, i01_, i10_, i11_, UA, UB, UC, UD);                \
        const _Float16* xg_ = xbase + g_ * 32;                              \
        QA = *(const uint4*)(xg_ + (long)i00_ * 256);                       \
        QB = *(const uint4*)(xg_ + (long)i01_ * 256);                       \
        QC = *(const uint4*)(xg_ + (long)i10_ * 256);                       \
        QD = *(const uint4*)(xg_ + (long)i11_ * 256);                       \
        const _Float16* ws_ = wt3 + (long)(S) * 8192 + (long)half * 4096;   \
        PA = *(const uint4*)(ws_ + bn * 32 + bp * 8);                       \
        PB = *(const uint4*)(ws_ + (bn + 64) * 32 + bp * 8);                \
    }

#define SAMP_WRITE(QA, QB, QC, QD, UA, UB, UC, UD, PA, PB, S) {             \
        *(uint4*)&Bld[bn][bp * 8] = PA;                                     \
        *(uint4*)&Bld[bn + 64][bp * 8] = PB;                                \
        float av_ = attnL[(S) * 64 + px];                                   \
        U4H8 x00_, x01_, x10_, x11_;                                        \
        x00_.u = QA; x01_.u = QB; x10_.u = QC; x11_.u = QD;                 \
        half8 rr_ = x00_.h * (_Float16)UA + x01_.h * (_Float16)UB          \
                  + x10_.h * (_Float16)UC + x11_.h * (_Float16)UD;          \
        rr_ = rr_ * (_Float16)av_;                                          \
        *(half8*)&Ald[px][cq * 8] = rr_;                                    \
    }

#define SAMP_MFMA() {                                                       \
        const int k0_ = (lane >> 4) * 8;                                    \
        half8 a0_ = *(const half8*)&Ald[mh * 32 + (lane & 15)][k0_];        \
        half8 a1_ = *(const half8*)&Ald[mh * 32 + 16 + (lane & 15)][k0_];   \
        _Pragma("unroll")                                                   \
        for (int j = 0; j < 4; ++j) {                                       \
            half8 bf_ = *(const half8*)&Bld[(nh * 4 + j) * 16 + (lane & 15)][k0_]; \
            acc[0][j] = __builtin_amdgcn_mfma_f32_16x16x32_f16(a0_, bf_, acc[0][j], 0, 0, 0); \
            acc[1][j] = __builtin_amdgcn_mfma_f32_16x16x32_f16(a1_, bf_, acc[1][j], 0, 0, 0); \
        }                                                                   \
    }

    // ---- preamble 2: issue stages 0,1; dy/dx for stage 2 ----
    {
        float dy0 = cbase[0 * HW + px], dx0 = cbase[1 * HW + px];
        SAMP_ISSUE(qa0, qb0, qc0, qd0, ua0, ub0, uc0, ud0, pA0, pB0, 0, dy0, dx0);
        float dy1 = cbase[2 * HW + px], dx1 = cbase[3 * HW + px];
        SAMP_ISSUE(qa1, qb1, qc1, qd1, ua1, ub1, uc1, ud1, pA1, pB1, 1, dy1, dx1);
        dyR = cbase[4 * HW + px]; dxR = cbase[5 * HW + px];
    }
    __syncthreads();   // attnL ready

    for (int ss = 0; ss < 72; ss += 2) {
        // ---- even stage (set 0) ----
        SAMP_WRITE(qa0, qb0, qc0, qd0, ua0, ub0, uc0, ud0, pA0, pB0, ss);
        if (ss + 2 < 72) {
            SAMP_ISSUE(qa0, qb0, qc0, qd0, ua0, ub0, uc0, ud0, pA0, pB0, ss + 2, dyR, dxR);
            int sf = ss + 3;
            dyR = cbase[(sf * 2) * HW + px]; dxR = cbase[(sf * 2 + 1) * HW + px];
        }
        __syncthreads();
        SAMP_MFMA();
        __syncthreads();
        // ---- odd stage (set 1) ----
        SAMP_WRITE(qa1, qb1, qc1, qd1, ua1, ub1, uc1, ud1, pA1, pB1, ss + 1);
        if (ss + 3 < 72) {
            SAMP_ISSUE(qa1, qb1, qc1, qd1, ua1, ub1, uc1, ud1, pA1, pB1, ss + 3, dyR, dxR);
            int sf = ss + 4;
            if (sf < 72) { dyR = cbase[(sf * 2) * HW + px]; dxR = cbase[(sf * 2 + 1) * HW + px]; }
        }
        __syncthreads();
        SAMP_MFMA();
        __syncthreads();
    }
#undef SAMP_ISSUE
#undef SAMP_WRITE
#undef SAMP_MFMA

    // ---- epilogue ----
    #pragma unroll
    for (int mi = 0; mi < 2; ++mi) {
        int px0 = mh * 32 + mi * 16 + (lane >> 4) * 4;
        #pragma unroll
        for (int j = 0; j < 4; ++j) {
            int oc = half * 128 + (nh * 4 + j) * 16 + (lane & 15);
            float bb = b_out[oc];
            float4 v = make_float4(acc[mi][j][0] + bb, acc[mi][j][1] + bb,
                                   acc[mi][j][2] + bb, acc[mi][j][3] + bb);
            *(float4*)&out[((long)b * OO + oc) * HW + h * WW + px0] = v;
        }
    }
}

// ---------------------------------------------------------------------------
extern "C" void kernel_launch(void* const* d_in, const int* in_sizes, int n_in,
                              void* d_out, int out_size, void* d_ws, size_t ws_size,
                              hipStream_t stream) {
    const float* x      = (const float*)d_in[0];
    const float* w_off  = (const float*)d_in[1];
    const float* b_off  = (const float*)d_in[2];
    const float* w_attn = (const float*)d_in[3];
    const float* b_attn = (const float*)d_in[4];
    const float* w_out  = (const float*)d_in[5];
    const float* b_out  = (const float*)d_in[6];
    float* out = (float*)d_out;

    _Float16* x_h     = (_Float16*)d_ws;                    // 8,388,608 halves
    float* conv_buf   = (float*)(x_h + 8388608);            // 7,077,888 floats
    _Float16* wt3     = (_Float16*)(conv_buf + 7077888);    // 589,824 halves
    _Float16* wt_conv = wt3 + 589824;                       // 516,096 halves
    float* bias_c     = (float*)(wt_conv + 516096);         // 224 floats

    repack_w<<<dim3((589824 + 255) / 256), dim3(256), 0, stream>>>(w_out, wt3);
    repack_conv<<<dim3((9 * NPAD * 256 + 255) / 256), dim3(256), 0, stream>>>(
        w_off, b_off, w_attn, b_attn, wt_conv, bias_c);
    repack_x<<<dim3(512), dim3(256), 0, stream>>>(x, x_h);

    conv_mfma<<<dim3(1024), dim3(256), 0, stream>>>(x_h, wt_conv, bias_c, conv_buf);

    sample_gemm_mfma<<<dim3(1024), dim3(256), 0, stream>>>(
        x_h, conv_buf, wt3, b_out, out);
}